// Round 9
// baseline (223.565 us; speedup 1.0000x reference)
//
#include <hip/hip_runtime.h>
#include <hip/hip_bf16.h>
#include <hip/hip_fp16.h>

static __device__ __forceinline__ float relu_f(float v) { return v > 0.f ? v : 0.f; }

typedef _Float16 half8 __attribute__((ext_vector_type(8)));
typedef float floatx4 __attribute__((ext_vector_type(4)));

// ---------------- fused init + fp16 cast of x + fp16 transpose-cast of W ----------------

__global__ void cast_init_kernel(const float4* __restrict__ x4, __half2* __restrict__ xh2,
                                 int n4, int* __restrict__ indeg8, int n8,
                                 float* __restrict__ gmax, float* __restrict__ gsum,
                                 float* __restrict__ gcnt, int gch, int g,
                                 const float* __restrict__ W, _Float16* __restrict__ wt) {
  int i = blockIdx.x * blockDim.x + threadIdx.x;
  if (i < n4) {
    float4 v = x4[i];
    xh2[2 * i + 0] = __floats2half2_rn(v.x, v.y);
    xh2[2 * i + 1] = __floats2half2_rn(v.z, v.w);
  }
  if (i < n8) indeg8[i] = 0;
  if (i < gch) { gmax[i] = 0.f; gsum[i] = 0.f; }
  if (i < g) gcnt[i] = 0.f;
  if (i < 128 * 128) {
    int k = i >> 7, nn = i & 127;
    wt[nn * 128 + k] = (_Float16)W[i];
  }
}

// one atomic per edge onto a blockIdx&7-private copy; rank packs (r<<3)|part
__global__ void count_rank_kernel(const int* __restrict__ dst, int* __restrict__ indeg8,
                                  int* __restrict__ rank, int E, int N) {
  int e = blockIdx.x * blockDim.x + threadIdx.x;
  if (e >= E) return;
  int part = blockIdx.x & 7;
  int r = atomicAdd(&indeg8[part * N + dst[e]], 1);
  rank[e] = (r << 3) | part;
}

// convert 8 copies -> per-(part,node) exclusive offsets (in place) + total indeg
__global__ void sum8_kernel(int* __restrict__ indeg8, int* __restrict__ indeg, int N) {
  int i = blockIdx.x * blockDim.x + threadIdx.x;
  if (i >= N) return;
  int run = 0;
  #pragma unroll
  for (int p = 0; p < 8; ++p) {
    int v = indeg8[p * N + i];
    indeg8[p * N + i] = run;  // exclusive prefix over parts
    run += v;
  }
  indeg[i] = run;
}

// ---------------- device-wide exclusive scan of indeg (2 kernels) ----------------

__global__ __launch_bounds__(1024) void scan_reduce_kernel(const int* __restrict__ indeg,
                                                           int* __restrict__ bsum, int n) {
  int i = blockIdx.x * 1024 + threadIdx.x;
  int v = (i < n) ? indeg[i] : 0;
  #pragma unroll
  for (int off = 32; off; off >>= 1) v += __shfl_down(v, off, 64);
  __shared__ int ws[16];
  int lane = threadIdx.x & 63, wid = threadIdx.x >> 6;
  if (lane == 0) ws[wid] = v;
  __syncthreads();
  if (threadIdx.x == 0) {
    int s = 0;
    #pragma unroll
    for (int j = 0; j < 16; ++j) s += ws[j];
    bsum[blockIdx.x] = s;
  }
}

__global__ __launch_bounds__(1024) void scan_write_kernel(const int* __restrict__ indeg,
    const int* __restrict__ bsum, int* __restrict__ rowptr, int n, int nb) {
  int i = blockIdx.x * 1024 + threadIdx.x;
  int v = (i < n) ? indeg[i] : 0;
  int lane = threadIdx.x & 63, wid = threadIdx.x >> 6;
  int inc = v;
  #pragma unroll
  for (int off = 1; off < 64; off <<= 1) {
    int u = __shfl_up(inc, off, 64);
    if (lane >= off) inc += u;
  }
  __shared__ int wtot[16];
  __shared__ int s_off;
  if (lane == 63) wtot[wid] = inc;
  if (threadIdx.x < 64) {
    int acc = 0;
    for (int base = 0; base < nb; base += 64) {
      int idx = base + (int)threadIdx.x;
      int val = (idx < nb && idx < (int)blockIdx.x) ? bsum[idx] : 0;
      #pragma unroll
      for (int off = 32; off; off >>= 1) val += __shfl_down(val, off, 64);
      if (threadIdx.x == 0) acc += val;
    }
    if (threadIdx.x == 0) s_off = acc;
  }
  __syncthreads();
  int woff = 0;
  for (int j = 0; j < wid; ++j) woff += wtot[j];
  int excl = s_off + woff + inc - v;
  if (i < n) {
    rowptr[i + 1] = excl + v;
    if (i == 0) rowptr[0] = 0;
  }
}

// no atomics: slot = rowptr[dst] + off8[part][dst] + r
__global__ void edge_fill_kernel(const int* __restrict__ src, const int* __restrict__ dst,
                                 const float* __restrict__ ew, const int* __restrict__ rank,
                                 const int* __restrict__ rowptr, const int* __restrict__ off8,
                                 int2* __restrict__ epack, int E, int N) {
  int e = blockIdx.x * blockDim.x + threadIdx.x;
  if (e >= E) return;
  int d = dst[e];
  int rk = rank[e];
  int slot = rowptr[d] + off8[(rk & 7) * N + d] + (rk >> 3);
  epack[slot] = make_int2(src[e], __float_as_int(ew[e]));
}

// deg[i] = 1 + sum of ew over row i (contiguous read); dinv = rsqrt
__global__ void row_dinv_kernel(const int* __restrict__ rowptr, const int2* __restrict__ epack,
                                float* __restrict__ dinv, int n) {
  int i = blockIdx.x * blockDim.x + threadIdx.x;
  if (i >= n) return;
  int s = rowptr[i], e = rowptr[i + 1];
  float d = 1.0f;  // self-loop weight
  for (int j = s; j < e; ++j) d += __int_as_float(epack[j].y);
  dinv[i] = (d > 0.f) ? rsqrtf(d) : 0.f;
}

// ---------------- aggregation: one wave per node, fp16 gathers, fp16 output ----------------

__global__ __launch_bounds__(256) void aggregate_kernel(const __half2* __restrict__ xh2,
    const float* __restrict__ dinv, const int* __restrict__ rowptr,
    const int2* __restrict__ epack, __half2* __restrict__ aggh2, int n) {
  int gid = blockIdx.x * blockDim.x + threadIdx.x;
  int node = gid >> 6;
  int lane = gid & 63;
  if (node >= n) return;
  float dn = dinv[node];
  float2 xv = __half22float2(xh2[node * 64 + lane]);
  float sw = dn * dn;  // self-loop norm
  float2 acc = make_float2(sw * xv.x, sw * xv.y);
  int s = rowptr[node], e = rowptr[node + 1];
  int j = s;
  for (; j + 8 <= e; j += 8) {
    int2 pk[8];
    #pragma unroll
    for (int u = 0; u < 8; ++u) pk[u] = epack[j + u];
    __half2 hx[8];
    float dw[8];
    #pragma unroll
    for (int u = 0; u < 8; ++u) {
      hx[u] = xh2[(size_t)pk[u].x * 64 + lane];
      dw[u] = dinv[pk[u].x];
    }
    #pragma unroll
    for (int u = 0; u < 8; ++u) {
      float w = dw[u] * __int_as_float(pk[u].y) * dn;
      float2 xc = __half22float2(hx[u]);
      acc.x += w * xc.x;
      acc.y += w * xc.y;
    }
  }
  for (; j < e; ++j) {
    int2 pk = epack[j];
    float w = dinv[pk.x] * __int_as_float(pk.y) * dn;
    float2 xc = __half22float2(xh2[(size_t)pk.x * 64 + lane]);
    acc.x += w * xc.x;
    acc.y += w * xc.y;
  }
  aggh2[node * 64 + lane] = __floats2half2_rn(acc.x, acc.y);
}

// ---------------- fused MFMA GEMM (aggh @ W + b, ReLU) + pooling ----------------

__global__ __launch_bounds__(256) void gemm_pool_kernel(const _Float16* __restrict__ aggh,
    const _Float16* __restrict__ wt, const float* __restrict__ bias,
    const int* __restrict__ batch, float* __restrict__ gmax, float* __restrict__ gsum,
    float* __restrict__ gcnt, int n) {
  __shared__ float sH[64 * 129];
  __shared__ int sBatch[64];
  int tid = threadIdx.x;
  int w = tid >> 6, lane = tid & 63;
  int quad = lane >> 4, c15 = lane & 15;
  int row0 = blockIdx.x * 64;
  int nb = n - row0; if (nb > 64) nb = 64;

  float bb[8];
  #pragma unroll
  for (int j = 0; j < 8; ++j) bb[j] = bias[j * 16 + c15];

  int arow = row0 + w * 16 + c15;
  if (arow >= n) arow = n - 1;  // clamped rows are discarded by the nb guard
  const half8* aptr = (const half8*)(aggh + (size_t)arow * 128 + quad * 8);

  floatx4 acc[8] = {};
  #pragma unroll
  for (int ks = 0; ks < 4; ++ks) {
    half8 af = aptr[ks * 4];  // +32 halves per k-step
    #pragma unroll
    for (int j = 0; j < 8; ++j) {
      const half8* bptr =
          (const half8*)(wt + (size_t)(j * 16 + c15) * 128 + ks * 32 + quad * 8);
      acc[j] = __builtin_amdgcn_mfma_f32_16x16x32_f16(af, *bptr, acc[j], 0, 0, 0);
    }
  }

  if (tid < nb) sBatch[tid] = batch[row0 + tid];

  #pragma unroll
  for (int j = 0; j < 8; ++j) {
    int col = j * 16 + c15;
    #pragma unroll
    for (int r = 0; r < 4; ++r) {
      int row = w * 16 + quad * 4 + r;
      if (row < nb) sH[row * 129 + col] = relu_f(acc[j][r] + bb[j]);
    }
  }
  __syncthreads();

  int c = tid & 127, hf = tid >> 7;
  int r0 = hf * 32, r1 = r0 + 32;
  if (r1 > nb) r1 = nb;
  if (r0 < r1) {
    int cur = sBatch[r0];
    float mx = 0.f, sm = 0.f;
    int cnt = 0;
    for (int r = r0; r < r1; ++r) {
      int g = sBatch[r];
      if (g != cur) {
        atomicMax((int*)&gmax[cur * 128 + c], __float_as_int(mx));
        atomicAdd(&gsum[cur * 128 + c], sm);
        if (c == 0) atomicAdd(&gcnt[cur], (float)cnt);
        mx = 0.f; sm = 0.f; cnt = 0; cur = g;
      }
      float v = sH[r * 129 + c];
      mx = fmaxf(mx, v);
      sm += v;
      ++cnt;
    }
    atomicMax((int*)&gmax[cur * 128 + c], __float_as_int(mx));
    atomicAdd(&gsum[cur * 128 + c], sm);
    if (c == 0) atomicAdd(&gcnt[cur], (float)cnt);
  }
}

// ---------------- MLP: one block per graph row ----------------

__global__ __launch_bounds__(128) void mlp_kernel(const float* __restrict__ gmax,
    const float* __restrict__ gsum, const float* __restrict__ gcnt,
    const float* __restrict__ rho,
    const float* __restrict__ w1, const float* __restrict__ b1,
    const float* __restrict__ w2, const float* __restrict__ b2,
    const float* __restrict__ w3, const float* __restrict__ b3,
    float* __restrict__ out) {
  __shared__ float s_in[257];
  __shared__ float s_z1[128];
  __shared__ float s_z2[128];
  int g = blockIdx.x, t = threadIdx.x;
  float inv_cnt = 1.f / fmaxf(gcnt[g], 1.f);
  s_in[t] = gmax[g * 128 + t];
  s_in[128 + t] = gsum[g * 128 + t] * inv_cnt;
  if (t == 0) s_in[256] = rho[g];
  __syncthreads();
  float s = b1[t];
  for (int k = 0; k < 257; ++k) s += s_in[k] * w1[k * 128 + t];
  s_z1[t] = relu_f(s);
  __syncthreads();
  s = b2[t];
  for (int k = 0; k < 128; ++k) s += s_z1[k] * w2[k * 128 + t];
  s_z2[t] = relu_f(s);
  __syncthreads();
  if (t < 36) {
    s = b3[t];
    for (int k = 0; k < 128; ++k) s += s_z2[k] * w3[k * 36 + t];
    out[g * 36 + t] = s;
  }
}

// ---------------- launch ----------------

extern "C" void kernel_launch(void* const* d_in, const int* in_sizes, int n_in,
                              void* d_out, int out_size, void* d_ws, size_t ws_size,
                              hipStream_t stream) {
  const float* x      = (const float*)d_in[0];
  const float* ew     = (const float*)d_in[1];
  const float* rho    = (const float*)d_in[2];
  const float* conv_w = (const float*)d_in[3];
  const float* conv_b = (const float*)d_in[4];
  const float* w1 = (const float*)d_in[5];
  const float* b1 = (const float*)d_in[6];
  const float* w2 = (const float*)d_in[7];
  const float* b2 = (const float*)d_in[8];
  const float* w3 = (const float*)d_in[9];
  const float* b3 = (const float*)d_in[10];
  const int* eidx  = (const int*)d_in[11];
  const int* batch = (const int*)d_in[12];

  const int N = in_sizes[0] / 128;
  const int E = in_sizes[1];
  const int G = in_sizes[2];
  const int* srcp = eidx;
  const int* dstp = eidx + E;

  const int NB = (N + 1023) / 1024;  // scan blocks (40 for N=40000)

  char* p = (char*)d_ws;
  auto carve = [&](size_t bytes) { char* r = p; p += (bytes + 255) & ~(size_t)255; return (void*)r; };
  float*    dinv   = (float*)   carve((size_t)N * 4);
  int*      indeg  = (int*)     carve((size_t)N * 4);
  int*      indeg8 = (int*)     carve((size_t)N * 8 * 4);
  int*      rowptr = (int*)     carve((size_t)(N + 1) * 4);
  int*      rank   = (int*)     carve((size_t)E * 4);
  int*      bsum   = (int*)     carve((size_t)NB * 4);
  int2*     epack  = (int2*)    carve((size_t)E * 8);
  __half2*  xh     = (__half2*) carve((size_t)N * 128 * 2);
  _Float16* aggh   = (_Float16*)carve((size_t)N * 128 * 2);
  _Float16* wt     = (_Float16*)carve((size_t)128 * 128 * 2);
  float*    gmax   = (float*)   carve((size_t)G * 128 * 4);
  float*    gsum   = (float*)   carve((size_t)G * 128 * 4);
  float*    gcnt   = (float*)   carve((size_t)G * 4);

  const int n4 = N * 32;  // float4 count of x (1.28M threads covers all init work)

  cast_init_kernel<<<(n4 + 255) / 256, 256, 0, stream>>>((const float4*)x, xh, n4,
                                                         indeg8, N * 8, gmax, gsum, gcnt,
                                                         G * 128, G, conv_w, wt);
  count_rank_kernel<<<(E + 255) / 256, 256, 0, stream>>>(dstp, indeg8, rank, E, N);
  sum8_kernel<<<(N + 255) / 256, 256, 0, stream>>>(indeg8, indeg, N);
  scan_reduce_kernel<<<NB, 1024, 0, stream>>>(indeg, bsum, N);
  scan_write_kernel<<<NB, 1024, 0, stream>>>(indeg, bsum, rowptr, N, NB);
  edge_fill_kernel<<<(E + 255) / 256, 256, 0, stream>>>(srcp, dstp, ew, rank, rowptr, indeg8,
                                                        epack, E, N);
  row_dinv_kernel<<<(N + 255) / 256, 256, 0, stream>>>(rowptr, epack, dinv, N);
  aggregate_kernel<<<(N + 3) / 4, 256, 0, stream>>>(xh, dinv, rowptr, epack,
                                                    (__half2*)aggh, N);
  gemm_pool_kernel<<<(N + 63) / 64, 256, 0, stream>>>(aggh, wt, conv_b, batch,
                                                      gmax, gsum, gcnt, N);
  mlp_kernel<<<G, 128, 0, stream>>>(gmax, gsum, gcnt, rho, w1, b1, w2, b2, w3, b3,
                                    (float*)d_out);
}

// Round 10
// 217.984 us; speedup vs baseline: 1.0256x; 1.0256x over previous
//
#include <hip/hip_runtime.h>
#include <hip/hip_bf16.h>
#include <hip/hip_fp16.h>

static __device__ __forceinline__ float relu_f(float v) { return v > 0.f ? v : 0.f; }

typedef _Float16 half8 __attribute__((ext_vector_type(8)));
typedef float floatx4 __attribute__((ext_vector_type(4)));

// ---------------- fused init + fp16 casts + epack zero-fill ----------------
// epack is pre-zeroed so CSR pad slots read as (src=0, w=0.0f): zero-weight
// gathers of row 0 that contribute exactly nothing.

__global__ void cast_init_kernel(const float4* __restrict__ x4, __half2* __restrict__ xh2,
                                 int n4, int* __restrict__ indeg, int n,
                                 float* __restrict__ gmax, float* __restrict__ gsum,
                                 float* __restrict__ gcnt, int gch, int g,
                                 const float* __restrict__ W, _Float16* __restrict__ wt,
                                 int2* __restrict__ epack, int epad) {
  int i = blockIdx.x * blockDim.x + threadIdx.x;
  if (i < n4) {
    float4 v = x4[i];
    xh2[2 * i + 0] = __floats2half2_rn(v.x, v.y);
    xh2[2 * i + 1] = __floats2half2_rn(v.z, v.w);
  }
  if (i < n) indeg[i] = 0;
  if (i < gch) { gmax[i] = 0.f; gsum[i] = 0.f; }
  if (i < g) gcnt[i] = 0.f;
  if (i < 128 * 128) {
    int k = i >> 7, nn = i & 127;
    wt[nn * 128 + k] = (_Float16)W[i];
  }
  if (i < epad) epack[i] = make_int2(0, 0);
}

// one atomic per edge; rank = within-bucket arrival order
__global__ void count_rank_kernel(const int* __restrict__ dst, int* __restrict__ indeg,
                                  int* __restrict__ rank, int E) {
  int e = blockIdx.x * blockDim.x + threadIdx.x;
  if (e >= E) return;
  rank[e] = atomicAdd(&indeg[dst[e]], 1);
}

// ---------------- device-wide exclusive scan of padded indeg (2 kernels) ----------------
// rows padded to multiples of 8 edges

__global__ __launch_bounds__(1024) void scan_reduce_kernel(const int* __restrict__ indeg,
                                                           int* __restrict__ bsum, int n) {
  int i = blockIdx.x * 1024 + threadIdx.x;
  int v = (i < n) ? ((indeg[i] + 7) & ~7) : 0;
  #pragma unroll
  for (int off = 32; off; off >>= 1) v += __shfl_down(v, off, 64);
  __shared__ int ws[16];
  int lane = threadIdx.x & 63, wid = threadIdx.x >> 6;
  if (lane == 0) ws[wid] = v;
  __syncthreads();
  if (threadIdx.x == 0) {
    int s = 0;
    #pragma unroll
    for (int j = 0; j < 16; ++j) s += ws[j];
    bsum[blockIdx.x] = s;
  }
}

__global__ __launch_bounds__(1024) void scan_write_kernel(const int* __restrict__ indeg,
    const int* __restrict__ bsum, int* __restrict__ rowptr, int n, int nb) {
  int i = blockIdx.x * 1024 + threadIdx.x;
  int v = (i < n) ? ((indeg[i] + 7) & ~7) : 0;
  int lane = threadIdx.x & 63, wid = threadIdx.x >> 6;
  int inc = v;
  #pragma unroll
  for (int off = 1; off < 64; off <<= 1) {
    int u = __shfl_up(inc, off, 64);
    if (lane >= off) inc += u;
  }
  __shared__ int wtot[16];
  __shared__ int s_off;
  if (lane == 63) wtot[wid] = inc;
  if (threadIdx.x < 64) {
    int acc = 0;
    for (int base = 0; base < nb; base += 64) {
      int idx = base + (int)threadIdx.x;
      int val = (idx < nb && idx < (int)blockIdx.x) ? bsum[idx] : 0;
      #pragma unroll
      for (int off = 32; off; off >>= 1) val += __shfl_down(val, off, 64);
      if (threadIdx.x == 0) acc += val;
    }
    if (threadIdx.x == 0) s_off = acc;
  }
  __syncthreads();
  int woff = 0;
  for (int j = 0; j < wid; ++j) woff += wtot[j];
  int excl = s_off + woff + inc - v;
  if (i < n) {
    rowptr[i + 1] = excl + v;
    if (i == 0) rowptr[0] = 0;
  }
}

// no atomics: slot = rowptr[dst] + rank (pad slots keep their zero fill)
__global__ void edge_fill_kernel(const int* __restrict__ src, const int* __restrict__ dst,
                                 const float* __restrict__ ew, const int* __restrict__ rank,
                                 const int* __restrict__ rowptr, int2* __restrict__ epack,
                                 int E) {
  int e = blockIdx.x * blockDim.x + threadIdx.x;
  if (e >= E) return;
  int d = dst[e];
  int slot = rowptr[d] + rank[e];
  epack[slot] = make_int2(src[e], __float_as_int(ew[e]));
}

// deg[i] = 1 + sum of ew over (padded) row i; pad weights are 0
__global__ void row_dinv_kernel(const int* __restrict__ rowptr, const int2* __restrict__ epack,
                                float* __restrict__ dinv, int n) {
  int i = blockIdx.x * blockDim.x + threadIdx.x;
  if (i >= n) return;
  int s = rowptr[i], e = rowptr[i + 1];
  float d = 1.0f;  // self-loop weight
  for (int j = s; j < e; ++j) d += __int_as_float(epack[j].y);
  dinv[i] = (d > 0.f) ? rsqrtf(d) : 0.f;
}

// ---------------- aggregation: one wave per node, uniform 8-deep pipelined loop ----------------
// rows are multiples of 8 edges -> no scalar tail, no divergence; pad entries
// gather row 0 with weight 0 (L1-hot, exact no-op).

__global__ __launch_bounds__(256) void aggregate_kernel(const __half2* __restrict__ xh2,
    const float* __restrict__ dinv, const int* __restrict__ rowptr,
    const int2* __restrict__ epack, __half2* __restrict__ aggh2, int n) {
  int gid = blockIdx.x * blockDim.x + threadIdx.x;
  int node = gid >> 6;
  int lane = gid & 63;
  if (node >= n) return;
  float dn = dinv[node];
  float2 xv = __half22float2(xh2[node * 64 + lane]);
  float sw = dn * dn;  // self-loop norm
  float2 acc = make_float2(sw * xv.x, sw * xv.y);
  int s = rowptr[node], e = rowptr[node + 1];
  for (int j = s; j < e; j += 8) {
    int2 pk[8];
    #pragma unroll
    for (int u = 0; u < 8; ++u) pk[u] = epack[j + u];
    __half2 hx[8];
    float dw[8];
    #pragma unroll
    for (int u = 0; u < 8; ++u) {
      hx[u] = xh2[(size_t)pk[u].x * 64 + lane];
      dw[u] = dinv[pk[u].x];
    }
    #pragma unroll
    for (int u = 0; u < 8; ++u) {
      float w = dw[u] * __int_as_float(pk[u].y) * dn;
      float2 xc = __half22float2(hx[u]);
      acc.x += w * xc.x;
      acc.y += w * xc.y;
    }
  }
  aggh2[node * 64 + lane] = __floats2half2_rn(acc.x, acc.y);
}

// ---------------- fused MFMA GEMM (aggh @ W + b, ReLU) + pooling ----------------

__global__ __launch_bounds__(256) void gemm_pool_kernel(const _Float16* __restrict__ aggh,
    const _Float16* __restrict__ wt, const float* __restrict__ bias,
    const int* __restrict__ batch, float* __restrict__ gmax, float* __restrict__ gsum,
    float* __restrict__ gcnt, int n) {
  __shared__ float sH[64 * 129];
  __shared__ int sBatch[64];
  int tid = threadIdx.x;
  int w = tid >> 6, lane = tid & 63;
  int quad = lane >> 4, c15 = lane & 15;
  int row0 = blockIdx.x * 64;
  int nb = n - row0; if (nb > 64) nb = 64;

  float bb[8];
  #pragma unroll
  for (int j = 0; j < 8; ++j) bb[j] = bias[j * 16 + c15];

  int arow = row0 + w * 16 + c15;
  if (arow >= n) arow = n - 1;  // clamped rows are discarded by the nb guard
  const half8* aptr = (const half8*)(aggh + (size_t)arow * 128 + quad * 8);

  floatx4 acc[8] = {};
  #pragma unroll
  for (int ks = 0; ks < 4; ++ks) {
    half8 af = aptr[ks * 4];  // +32 halves per k-step
    #pragma unroll
    for (int j = 0; j < 8; ++j) {
      const half8* bptr =
          (const half8*)(wt + (size_t)(j * 16 + c15) * 128 + ks * 32 + quad * 8);
      acc[j] = __builtin_amdgcn_mfma_f32_16x16x32_f16(af, *bptr, acc[j], 0, 0, 0);
    }
  }

  if (tid < nb) sBatch[tid] = batch[row0 + tid];

  #pragma unroll
  for (int j = 0; j < 8; ++j) {
    int col = j * 16 + c15;
    #pragma unroll
    for (int r = 0; r < 4; ++r) {
      int row = w * 16 + quad * 4 + r;
      if (row < nb) sH[row * 129 + col] = relu_f(acc[j][r] + bb[j]);
    }
  }
  __syncthreads();

  int c = tid & 127, hf = tid >> 7;
  int r0 = hf * 32, r1 = r0 + 32;
  if (r1 > nb) r1 = nb;
  if (r0 < r1) {
    int cur = sBatch[r0];
    float mx = 0.f, sm = 0.f;
    int cnt = 0;
    for (int r = r0; r < r1; ++r) {
      int g = sBatch[r];
      if (g != cur) {
        atomicMax((int*)&gmax[cur * 128 + c], __float_as_int(mx));
        atomicAdd(&gsum[cur * 128 + c], sm);
        if (c == 0) atomicAdd(&gcnt[cur], (float)cnt);
        mx = 0.f; sm = 0.f; cnt = 0; cur = g;
      }
      float v = sH[r * 129 + c];
      mx = fmaxf(mx, v);
      sm += v;
      ++cnt;
    }
    atomicMax((int*)&gmax[cur * 128 + c], __float_as_int(mx));
    atomicAdd(&gsum[cur * 128 + c], sm);
    if (c == 0) atomicAdd(&gcnt[cur], (float)cnt);
  }
}

// ---------------- MLP: one block per graph row ----------------

__global__ __launch_bounds__(128) void mlp_kernel(const float* __restrict__ gmax,
    const float* __restrict__ gsum, const float* __restrict__ gcnt,
    const float* __restrict__ rho,
    const float* __restrict__ w1, const float* __restrict__ b1,
    const float* __restrict__ w2, const float* __restrict__ b2,
    const float* __restrict__ w3, const float* __restrict__ b3,
    float* __restrict__ out) {
  __shared__ float s_in[257];
  __shared__ float s_z1[128];
  __shared__ float s_z2[128];
  int g = blockIdx.x, t = threadIdx.x;
  float inv_cnt = 1.f / fmaxf(gcnt[g], 1.f);
  s_in[t] = gmax[g * 128 + t];
  s_in[128 + t] = gsum[g * 128 + t] * inv_cnt;
  if (t == 0) s_in[256] = rho[g];
  __syncthreads();
  float s = b1[t];
  for (int k = 0; k < 257; ++k) s += s_in[k] * w1[k * 128 + t];
  s_z1[t] = relu_f(s);
  __syncthreads();
  s = b2[t];
  for (int k = 0; k < 128; ++k) s += s_z1[k] * w2[k * 128 + t];
  s_z2[t] = relu_f(s);
  __syncthreads();
  if (t < 36) {
    s = b3[t];
    for (int k = 0; k < 128; ++k) s += s_z2[k] * w3[k * 36 + t];
    out[g * 36 + t] = s;
  }
}

// ---------------- launch ----------------

extern "C" void kernel_launch(void* const* d_in, const int* in_sizes, int n_in,
                              void* d_out, int out_size, void* d_ws, size_t ws_size,
                              hipStream_t stream) {
  const float* x      = (const float*)d_in[0];
  const float* ew     = (const float*)d_in[1];
  const float* rho    = (const float*)d_in[2];
  const float* conv_w = (const float*)d_in[3];
  const float* conv_b = (const float*)d_in[4];
  const float* w1 = (const float*)d_in[5];
  const float* b1 = (const float*)d_in[6];
  const float* w2 = (const float*)d_in[7];
  const float* b2 = (const float*)d_in[8];
  const float* w3 = (const float*)d_in[9];
  const float* b3 = (const float*)d_in[10];
  const int* eidx  = (const int*)d_in[11];
  const int* batch = (const int*)d_in[12];

  const int N = in_sizes[0] / 128;
  const int E = in_sizes[1];
  const int G = in_sizes[2];
  const int* srcp = eidx;
  const int* dstp = eidx + E;

  const int NB = (N + 1023) / 1024;   // scan blocks (40 for N=40000)
  const int EPAD = E + 8 * N;         // upper bound on padded edge count

  char* p = (char*)d_ws;
  auto carve = [&](size_t bytes) { char* r = p; p += (bytes + 255) & ~(size_t)255; return (void*)r; };
  float*    dinv   = (float*)   carve((size_t)N * 4);
  int*      indeg  = (int*)     carve((size_t)N * 4);
  int*      rowptr = (int*)     carve((size_t)(N + 1) * 4);
  int*      rank   = (int*)     carve((size_t)E * 4);
  int*      bsum   = (int*)     carve((size_t)NB * 4);
  int2*     epack  = (int2*)    carve((size_t)EPAD * 8);
  __half2*  xh     = (__half2*) carve((size_t)N * 128 * 2);
  _Float16* aggh   = (_Float16*)carve((size_t)N * 128 * 2);
  _Float16* wt     = (_Float16*)carve((size_t)128 * 128 * 2);
  float*    gmax   = (float*)   carve((size_t)G * 128 * 4);
  float*    gsum   = (float*)   carve((size_t)G * 128 * 4);
  float*    gcnt   = (float*)   carve((size_t)G * 4);

  const int n4 = N * 32;  // float4 count of x; 1.28M threads >= EPAD (~960k)

  cast_init_kernel<<<(n4 + 255) / 256, 256, 0, stream>>>((const float4*)x, xh, n4,
                                                         indeg, N, gmax, gsum, gcnt,
                                                         G * 128, G, conv_w, wt,
                                                         epack, EPAD);
  count_rank_kernel<<<(E + 255) / 256, 256, 0, stream>>>(dstp, indeg, rank, E);
  scan_reduce_kernel<<<NB, 1024, 0, stream>>>(indeg, bsum, N);
  scan_write_kernel<<<NB, 1024, 0, stream>>>(indeg, bsum, rowptr, N, NB);
  edge_fill_kernel<<<(E + 255) / 256, 256, 0, stream>>>(srcp, dstp, ew, rank, rowptr, epack, E);
  row_dinv_kernel<<<(N + 255) / 256, 256, 0, stream>>>(rowptr, epack, dinv, N);
  aggregate_kernel<<<(N + 3) / 4, 256, 0, stream>>>(xh, dinv, rowptr, epack,
                                                    (__half2*)aggh, N);
  gemm_pool_kernel<<<(N + 63) / 64, 256, 0, stream>>>(aggh, wt, conv_b, batch,
                                                      gmax, gsum, gcnt, N);
  mlp_kernel<<<G, 128, 0, stream>>>(gmax, gsum, gcnt, rho, w1, b1, w2, b2, w3, b3,
                                    (float*)d_out);
}

// Round 11
// 215.599 us; speedup vs baseline: 1.0369x; 1.0111x over previous
//
#include <hip/hip_runtime.h>
#include <hip/hip_bf16.h>
#include <hip/hip_fp16.h>

static __device__ __forceinline__ float relu_f(float v) { return v > 0.f ? v : 0.f; }

typedef _Float16 half8 __attribute__((ext_vector_type(8)));
typedef float floatx4 __attribute__((ext_vector_type(4)));

// ---------------- fused init + fp16 casts + epack zero-fill ----------------
// epack pre-zeroed so CSR pad slots read as (src=0, w=0.0f): zero-weight
// gathers of row 0 that contribute exactly nothing.

__global__ void cast_init_kernel(const float4* __restrict__ x4, __half2* __restrict__ xh2,
                                 int n4, int* __restrict__ indeg, int n,
                                 float* __restrict__ gmax, float* __restrict__ gsum,
                                 float* __restrict__ gcnt, int gch, int g,
                                 const float* __restrict__ W, _Float16* __restrict__ wt,
                                 int2* __restrict__ epack, int epad) {
  int i = blockIdx.x * blockDim.x + threadIdx.x;
  if (i < n4) {
    float4 v = x4[i];
    xh2[2 * i + 0] = __floats2half2_rn(v.x, v.y);
    xh2[2 * i + 1] = __floats2half2_rn(v.z, v.w);
  }
  if (i < n) indeg[i] = 0;
  if (i < gch) { gmax[i] = 0.f; gsum[i] = 0.f; }
  if (i < g) gcnt[i] = 0.f;
  if (i < 128 * 128) {
    int k = i >> 7, nn = i & 127;
    wt[nn * 128 + k] = (_Float16)W[i];
  }
  if (i < epad) epack[i] = make_int2(0, 0);
}

// one atomic per edge; rank = within-bucket arrival order
__global__ void count_rank_kernel(const int* __restrict__ dst, int* __restrict__ indeg,
                                  int* __restrict__ rank, int E) {
  int e = blockIdx.x * blockDim.x + threadIdx.x;
  if (e >= E) return;
  rank[e] = atomicAdd(&indeg[dst[e]], 1);
}

// ---------------- device-wide exclusive scan of padded indeg (2 kernels) ----------------
// rows padded to multiples of 4 edges

__global__ __launch_bounds__(1024) void scan_reduce_kernel(const int* __restrict__ indeg,
                                                           int* __restrict__ bsum, int n) {
  int i = blockIdx.x * 1024 + threadIdx.x;
  int v = (i < n) ? ((indeg[i] + 3) & ~3) : 0;
  #pragma unroll
  for (int off = 32; off; off >>= 1) v += __shfl_down(v, off, 64);
  __shared__ int ws[16];
  int lane = threadIdx.x & 63, wid = threadIdx.x >> 6;
  if (lane == 0) ws[wid] = v;
  __syncthreads();
  if (threadIdx.x == 0) {
    int s = 0;
    #pragma unroll
    for (int j = 0; j < 16; ++j) s += ws[j];
    bsum[blockIdx.x] = s;
  }
}

__global__ __launch_bounds__(1024) void scan_write_kernel(const int* __restrict__ indeg,
    const int* __restrict__ bsum, int* __restrict__ rowptr, int n, int nb) {
  int i = blockIdx.x * 1024 + threadIdx.x;
  int v = (i < n) ? ((indeg[i] + 3) & ~3) : 0;
  int lane = threadIdx.x & 63, wid = threadIdx.x >> 6;
  int inc = v;
  #pragma unroll
  for (int off = 1; off < 64; off <<= 1) {
    int u = __shfl_up(inc, off, 64);
    if (lane >= off) inc += u;
  }
  __shared__ int wtot[16];
  __shared__ int s_off;
  if (lane == 63) wtot[wid] = inc;
  if (threadIdx.x < 64) {
    int acc = 0;
    for (int base = 0; base < nb; base += 64) {
      int idx = base + (int)threadIdx.x;
      int val = (idx < nb && idx < (int)blockIdx.x) ? bsum[idx] : 0;
      #pragma unroll
      for (int off = 32; off; off >>= 1) val += __shfl_down(val, off, 64);
      if (threadIdx.x == 0) acc += val;
    }
    if (threadIdx.x == 0) s_off = acc;
  }
  __syncthreads();
  int woff = 0;
  for (int j = 0; j < wid; ++j) woff += wtot[j];
  int excl = s_off + woff + inc - v;
  if (i < n) {
    rowptr[i + 1] = excl + v;
    if (i == 0) rowptr[0] = 0;
  }
}

// no atomics: slot = rowptr[dst] + rank (pad slots keep their zero fill)
__global__ void edge_fill_kernel(const int* __restrict__ src, const int* __restrict__ dst,
                                 const float* __restrict__ ew, const int* __restrict__ rank,
                                 const int* __restrict__ rowptr, int2* __restrict__ epack,
                                 int E) {
  int e = blockIdx.x * blockDim.x + threadIdx.x;
  if (e >= E) return;
  int d = dst[e];
  int slot = rowptr[d] + rank[e];
  epack[slot] = make_int2(src[e], __float_as_int(ew[e]));
}

// deg[i] = 1 + sum of ew over (padded) row i; pad weights are 0
__global__ void row_dinv_kernel(const int* __restrict__ rowptr, const int2* __restrict__ epack,
                                float* __restrict__ dinv, int n) {
  int i = blockIdx.x * blockDim.x + threadIdx.x;
  if (i >= n) return;
  int s = rowptr[i], e = rowptr[i + 1];
  float d = 1.0f;  // self-loop weight
  for (int j = s; j < e; ++j) d += __int_as_float(epack[j].y);
  dinv[i] = (d > 0.f) ? rsqrtf(d) : 0.f;
}

// ---------------- aggregation: 4 nodes per wave, 16 B per lane ----------------
// Row = 128 halves = 16 lanes x half8. Lane group (lane>>4) owns one node; a
// single gather instruction covers 4 rows = 1 KB. Rows padded to multiples of
// 4 -> uniform 4-deep unrolled loop per group; pad entries gather row 0 with
// weight 0 (exact no-op). Group loop bounds diverge across the wave (max of 4
// degrees) -- masked lanes idle, acceptable.

__global__ __launch_bounds__(256) void aggregate_kernel(const half8* __restrict__ xh8,
    const float* __restrict__ dinv, const int* __restrict__ rowptr,
    const int2* __restrict__ epack, half8* __restrict__ aggh8, int n) {
  int gid = blockIdx.x * blockDim.x + threadIdx.x;
  int lane = gid & 63;
  int grp = lane >> 4, sub = lane & 15;
  int node = (gid >> 6) * 4 + grp;
  if (node >= n) return;
  float dn = dinv[node];
  half8 xv = xh8[(size_t)node * 16 + sub];
  float sw = dn * dn;  // self-loop norm
  float acc[8];
  #pragma unroll
  for (int c = 0; c < 8; ++c) acc[c] = sw * (float)xv[c];
  int s = rowptr[node], e = rowptr[node + 1];
  for (int j = s; j < e; j += 4) {
    int2 pk0 = epack[j + 0];
    int2 pk1 = epack[j + 1];
    int2 pk2 = epack[j + 2];
    int2 pk3 = epack[j + 3];
    half8 h0 = xh8[(size_t)pk0.x * 16 + sub];
    half8 h1 = xh8[(size_t)pk1.x * 16 + sub];
    half8 h2 = xh8[(size_t)pk2.x * 16 + sub];
    half8 h3 = xh8[(size_t)pk3.x * 16 + sub];
    float w0 = dinv[pk0.x] * __int_as_float(pk0.y) * dn;
    float w1 = dinv[pk1.x] * __int_as_float(pk1.y) * dn;
    float w2 = dinv[pk2.x] * __int_as_float(pk2.y) * dn;
    float w3 = dinv[pk3.x] * __int_as_float(pk3.y) * dn;
    #pragma unroll
    for (int c = 0; c < 8; ++c) {
      acc[c] += w0 * (float)h0[c];
      acc[c] += w1 * (float)h1[c];
      acc[c] += w2 * (float)h2[c];
      acc[c] += w3 * (float)h3[c];
    }
  }
  half8 outv;
  #pragma unroll
  for (int c = 0; c < 8; ++c) outv[c] = (_Float16)acc[c];
  aggh8[(size_t)node * 16 + sub] = outv;
}

// ---------------- fused MFMA GEMM (aggh @ W + b, ReLU) + pooling ----------------

__global__ __launch_bounds__(256) void gemm_pool_kernel(const _Float16* __restrict__ aggh,
    const _Float16* __restrict__ wt, const float* __restrict__ bias,
    const int* __restrict__ batch, float* __restrict__ gmax, float* __restrict__ gsum,
    float* __restrict__ gcnt, int n) {
  __shared__ float sH[64 * 129];
  __shared__ int sBatch[64];
  int tid = threadIdx.x;
  int w = tid >> 6, lane = tid & 63;
  int quad = lane >> 4, c15 = lane & 15;
  int row0 = blockIdx.x * 64;
  int nb = n - row0; if (nb > 64) nb = 64;

  float bb[8];
  #pragma unroll
  for (int j = 0; j < 8; ++j) bb[j] = bias[j * 16 + c15];

  int arow = row0 + w * 16 + c15;
  if (arow >= n) arow = n - 1;  // clamped rows are discarded by the nb guard
  const half8* aptr = (const half8*)(aggh + (size_t)arow * 128 + quad * 8);

  floatx4 acc[8] = {};
  #pragma unroll
  for (int ks = 0; ks < 4; ++ks) {
    half8 af = aptr[ks * 4];  // +32 halves per k-step
    #pragma unroll
    for (int j = 0; j < 8; ++j) {
      const half8* bptr =
          (const half8*)(wt + (size_t)(j * 16 + c15) * 128 + ks * 32 + quad * 8);
      acc[j] = __builtin_amdgcn_mfma_f32_16x16x32_f16(af, *bptr, acc[j], 0, 0, 0);
    }
  }

  if (tid < nb) sBatch[tid] = batch[row0 + tid];

  #pragma unroll
  for (int j = 0; j < 8; ++j) {
    int col = j * 16 + c15;
    #pragma unroll
    for (int r = 0; r < 4; ++r) {
      int row = w * 16 + quad * 4 + r;
      if (row < nb) sH[row * 129 + col] = relu_f(acc[j][r] + bb[j]);
    }
  }
  __syncthreads();

  int c = tid & 127, hf = tid >> 7;
  int r0 = hf * 32, r1 = r0 + 32;
  if (r1 > nb) r1 = nb;
  if (r0 < r1) {
    int cur = sBatch[r0];
    float mx = 0.f, sm = 0.f;
    int cnt = 0;
    for (int r = r0; r < r1; ++r) {
      int g = sBatch[r];
      if (g != cur) {
        atomicMax((int*)&gmax[cur * 128 + c], __float_as_int(mx));
        atomicAdd(&gsum[cur * 128 + c], sm);
        if (c == 0) atomicAdd(&gcnt[cur], (float)cnt);
        mx = 0.f; sm = 0.f; cnt = 0; cur = g;
      }
      float v = sH[r * 129 + c];
      mx = fmaxf(mx, v);
      sm += v;
      ++cnt;
    }
    atomicMax((int*)&gmax[cur * 128 + c], __float_as_int(mx));
    atomicAdd(&gsum[cur * 128 + c], sm);
    if (c == 0) atomicAdd(&gcnt[cur], (float)cnt);
  }
}

// ---------------- MLP: one block per graph row ----------------

__global__ __launch_bounds__(128) void mlp_kernel(const float* __restrict__ gmax,
    const float* __restrict__ gsum, const float* __restrict__ gcnt,
    const float* __restrict__ rho,
    const float* __restrict__ w1, const float* __restrict__ b1,
    const float* __restrict__ w2, const float* __restrict__ b2,
    const float* __restrict__ w3, const float* __restrict__ b3,
    float* __restrict__ out) {
  __shared__ float s_in[257];
  __shared__ float s_z1[128];
  __shared__ float s_z2[128];
  int g = blockIdx.x, t = threadIdx.x;
  float inv_cnt = 1.f / fmaxf(gcnt[g], 1.f);
  s_in[t] = gmax[g * 128 + t];
  s_in[128 + t] = gsum[g * 128 + t] * inv_cnt;
  if (t == 0) s_in[256] = rho[g];
  __syncthreads();
  float s = b1[t];
  for (int k = 0; k < 257; ++k) s += s_in[k] * w1[k * 128 + t];
  s_z1[t] = relu_f(s);
  __syncthreads();
  s = b2[t];
  for (int k = 0; k < 128; ++k) s += s_z1[k] * w2[k * 128 + t];
  s_z2[t] = relu_f(s);
  __syncthreads();
  if (t < 36) {
    s = b3[t];
    for (int k = 0; k < 128; ++k) s += s_z2[k] * w3[k * 36 + t];
    out[g * 36 + t] = s;
  }
}

// ---------------- launch ----------------

extern "C" void kernel_launch(void* const* d_in, const int* in_sizes, int n_in,
                              void* d_out, int out_size, void* d_ws, size_t ws_size,
                              hipStream_t stream) {
  const float* x      = (const float*)d_in[0];
  const float* ew     = (const float*)d_in[1];
  const float* rho    = (const float*)d_in[2];
  const float* conv_w = (const float*)d_in[3];
  const float* conv_b = (const float*)d_in[4];
  const float* w1 = (const float*)d_in[5];
  const float* b1 = (const float*)d_in[6];
  const float* w2 = (const float*)d_in[7];
  const float* b2 = (const float*)d_in[8];
  const float* w3 = (const float*)d_in[9];
  const float* b3 = (const float*)d_in[10];
  const int* eidx  = (const int*)d_in[11];
  const int* batch = (const int*)d_in[12];

  const int N = in_sizes[0] / 128;
  const int E = in_sizes[1];
  const int G = in_sizes[2];
  const int* srcp = eidx;
  const int* dstp = eidx + E;

  const int NB = (N + 1023) / 1024;   // scan blocks (40 for N=40000)
  const int EPAD = E + 4 * N;         // upper bound on padded edge count

  char* p = (char*)d_ws;
  auto carve = [&](size_t bytes) { char* r = p; p += (bytes + 255) & ~(size_t)255; return (void*)r; };
  float*    dinv   = (float*)   carve((size_t)N * 4);
  int*      indeg  = (int*)     carve((size_t)N * 4);
  int*      rowptr = (int*)     carve((size_t)(N + 1) * 4);
  int*      rank   = (int*)     carve((size_t)E * 4);
  int*      bsum   = (int*)     carve((size_t)NB * 4);
  int2*     epack  = (int2*)    carve((size_t)EPAD * 8);
  __half2*  xh     = (__half2*) carve((size_t)N * 128 * 2);
  _Float16* aggh   = (_Float16*)carve((size_t)N * 128 * 2);
  _Float16* wt     = (_Float16*)carve((size_t)128 * 128 * 2);
  float*    gmax   = (float*)   carve((size_t)G * 128 * 4);
  float*    gsum   = (float*)   carve((size_t)G * 128 * 4);
  float*    gcnt   = (float*)   carve((size_t)G * 4);

  const int n4 = N * 32;  // float4 count of x; 1.28M threads >= EPAD (~800k)

  cast_init_kernel<<<(n4 + 255) / 256, 256, 0, stream>>>((const float4*)x, xh, n4,
                                                         indeg, N, gmax, gsum, gcnt,
                                                         G * 128, G, conv_w, wt,
                                                         epack, EPAD);
  count_rank_kernel<<<(E + 255) / 256, 256, 0, stream>>>(dstp, indeg, rank, E);
  scan_reduce_kernel<<<NB, 1024, 0, stream>>>(indeg, bsum, N);
  scan_write_kernel<<<NB, 1024, 0, stream>>>(indeg, bsum, rowptr, N, NB);
  edge_fill_kernel<<<(E + 255) / 256, 256, 0, stream>>>(srcp, dstp, ew, rank, rowptr, epack, E);
  row_dinv_kernel<<<(N + 255) / 256, 256, 0, stream>>>(rowptr, epack, dinv, N);
  // 4 nodes per wave -> 16 nodes per 256-thread block
  aggregate_kernel<<<(N + 15) / 16, 256, 0, stream>>>((const half8*)xh, dinv, rowptr, epack,
                                                      (half8*)aggh, N);
  gemm_pool_kernel<<<(N + 63) / 64, 256, 0, stream>>>(aggh, wt, conv_b, batch,
                                                      gmax, gsum, gcnt, N);
  mlp_kernel<<<G, 128, 0, stream>>>(gmax, gsum, gcnt, rho, w1, b1, w2, b2, w3, b3,
                                    (float*)d_out);
}